// Round 3
// baseline (1087.976 us; speedup 1.0000x reference)
//
#include <hip/hip_runtime.h>

// ---------------------------------------------------------------------------
// DeepSeek MoE forward on MI355X (gfx950).
// R3 pipeline (7 launches): zero_meta -> router -> finalize -> gather ->
//   zero_out -> gemm1 (routed+shared, fused fp32->bf16 B-staging) ->
//   gemm2 (routed+shared, all-atomic epilogue).
// GEMMs: 128x128 tile, BK=32, mfma_f32_16x16x32_bf16; A via global_load_lds
//   width=16 (bf16); B reg-staged: global fp32 -> v_cvt_pk_bf16_f32 ->
//   ds_write_b128 (removes the conv kernels' 600MB HBM round-trip).
// Shared expert = "expert 8": tok=s, w=1.0, A read from xb directly.
// R1 lesson: XCD swizzle must remap ACTIVE tiles only (early-exit blocks
//   starved XCDs 4-7 -> 8% occupancy). R2 fixed: FETCH 425->95MB on G2.
// ---------------------------------------------------------------------------

typedef unsigned short u16;
typedef unsigned int u32;

typedef short bf16x8 __attribute__((ext_vector_type(8)));
typedef float f32x4 __attribute__((ext_vector_type(4)));

#define GLD16(g, l)                                                            \
  __builtin_amdgcn_global_load_lds(                                            \
      (const __attribute__((address_space(1))) void*)(g),                      \
      (__attribute__((address_space(3))) void*)(l), 16, 0, 0)

__device__ __forceinline__ u32 rne16(float f) {
  u32 u = __float_as_uint(f);
  return (u + 0x7fffu + ((u >> 16) & 1u)) >> 16;
}
__device__ __forceinline__ u16 bf16of(float f) { return (u16)rne16(f); }

// pack 2 fp32 -> 2 bf16 (RNE) in one VALU op
__device__ __forceinline__ u32 cvt2(float lo, float hi) {
  u32 r;
  asm("v_cvt_pk_bf16_f32 %0, %1, %2" : "=v"(r) : "v"(lo), "v"(hi));
  return r;
}

// Bijective XCD-chunk remap (m204) over the first nact logical ids.
__device__ __forceinline__ int xcd_remap_act(int lin, int nact) {
  int xcd = lin & 7, idx = lin >> 3;
  int q = nact >> 3, r = nact & 7;
  int base = xcd < r ? xcd * (q + 1) : r * (q + 1) + (xcd - r) * q;
  return base + idx;
}

// ---------------- meta layout (int* meta at ws+0) ----------------
// [0..7] cnt[e] routed   [8] cnt shared (=4096)
// [16..25] base[e], base[8]=routed total (gather bound), base[9]=grand total
// float at meta+32 : z-loss accumulator

__global__ void zero_meta_kernel(int* __restrict__ meta) {
  int t = threadIdx.x;
  if (t < 8) meta[t] = 0;
  if (t == 8) ((float*)(meta + 32))[0] = 0.0f;
}

__global__ void zero_out_kernel(float4* __restrict__ o) {
  o[blockIdx.x * 256 + threadIdx.x] = make_float4(0.f, 0.f, 0.f, 0.f);
}

// one wave (64 threads) per token
__global__ void router_kernel(const float* __restrict__ x,
                              const float* __restrict__ rw,
                              u16* __restrict__ xb, int* __restrict__ tlist,
                              float* __restrict__ gwv, int* __restrict__ meta) {
  int tok = blockIdx.x;
  int lane = threadIdx.x;
  const float* xr = x + (size_t)tok * 1024;
  float acc[8] = {0.f, 0.f, 0.f, 0.f, 0.f, 0.f, 0.f, 0.f};
#pragma unroll
  for (int c = 0; c < 16; c++) {
    float xv = xr[lane + 64 * c];
    xb[(size_t)tok * 1024 + lane + 64 * c] = bf16of(xv);
#pragma unroll
    for (int e = 0; e < 8; e++) acc[e] += xv * rw[e * 1024 + lane + 64 * c];
  }
#pragma unroll
  for (int e = 0; e < 8; e++) {
    float v = acc[e];
    for (int m = 32; m > 0; m >>= 1) v += __shfl_xor(v, m, 64);
    acc[e] = v;
  }
  if (lane == 0) {
    float z = 0.f;
#pragma unroll
    for (int e = 0; e < 8; e++) z += acc[e] * acc[e];
    atomicAdd((float*)(meta + 32), z);
    int i1 = 0;
    float b1 = acc[0];
#pragma unroll
    for (int e = 1; e < 8; e++)
      if (acc[e] > b1) { b1 = acc[e]; i1 = e; }
    int i2 = -1;
    float b2 = -3.0e38f;
#pragma unroll
    for (int e = 0; e < 8; e++)
      if (e != i1 && acc[e] > b2) { b2 = acc[e]; i2 = e; }
    float w1 = 1.0f / (1.0f + __expf(b2 - b1));  // = p1/(p1+p2)
    float w2 = 1.0f - w1;
    int s1 = atomicAdd(&meta[i1], 1);
    tlist[i1 * 4096 + s1] = tok;
    gwv[i1 * 4096 + s1] = w1;
    int s2 = atomicAdd(&meta[i2], 1);
    tlist[i2 * 4096 + s2] = tok;
    gwv[i2 * 4096 + s2] = w2;
  }
}

__global__ void finalize_kernel(int* __restrict__ meta, float* __restrict__ out) {
  if (threadIdx.x == 0) {
    int* basep = meta + 16;
    int base = 0;
    float lb = 0.f;
    const float invsum = 1.0f / 12288.0f;  // sum loads = 8192 + 4096
    const float ideal = 1.0f / 9.0f;
    for (int e = 0; e < 8; e++) {
      int c = meta[e];
      int p = (c + 127) & ~127;
      basep[e] = base;
      base += p;
      float d = (float)c * invsum - ideal;
      lb += d * d;
    }
    basep[8] = base;           // routed total
    basep[9] = base + 4096;    // + shared rows
    meta[8] = 4096;            // shared cnt
    float dsh = 4096.0f * invsum - ideal;
    lb += dsh * dsh;
    lb *= (1.0f / 9.0f);
    float z = ((float*)(meta + 32))[0] * (1.0f / 4096.0f);
    out[4194304] = 0.01f * lb + 0.01f * z;  // total_aux_loss
  }
}

// one block (128 thr) per gathered row; zero pads (routed rows only)
__global__ void gather_kernel(const u16* __restrict__ xb, u16* __restrict__ Ag,
                              const int* __restrict__ tlist,
                              const int* __restrict__ meta) {
  int r = blockIdx.x;
  int t = threadIdx.x;
  const int* base = meta + 16;
  int total = base[8];
  uint4 val = make_uint4(0u, 0u, 0u, 0u);
  if (r < total) {
    int e = 0;
#pragma unroll
    for (int q = 1; q < 8; q++)
      if (r >= base[q]) e = q;
    int s = r - base[e];
    if (s < meta[e]) {
      int tok = tlist[e * 4096 + s];
      val = *((const uint4*)(xb + (size_t)tok * 1024) + t);
    }
  }
  *((uint4*)(Ag + (size_t)r * 1024) + t) = val;
}

// ---------------- GEMM1: h = silu(A@Wg^T) * (A@Wu^T), bf16 out -------------
// A: Ag [routed rows,1024] bf16 / xb for shared region; Wg/Wu fp32 [E][4096][1024]
// Hout [base[9] rows, 4096] bf16
__global__ __launch_bounds__(256, 2) void gemm1_kernel(
    const u16* __restrict__ Ag, const u16* __restrict__ xb,
    const float* __restrict__ Wg, const float* __restrict__ Wu,
    const float* __restrict__ sg, const float* __restrict__ su,
    u16* __restrict__ Hout, const int* __restrict__ meta) {
  __shared__ u16 sA[128 * 32];
  __shared__ u16 sBg[128 * 32];
  __shared__ u16 sBu[128 * 32];

  const int* base = meta + 16;
  int gx = gridDim.x;
  int nby = base[9] >> 7;
  int nact = nby * gx;
  int lin = blockIdx.x + gx * blockIdx.y;
  if (lin >= nact) return;
  int wg = xcd_remap_act(lin, nact);
  int per = 8 * gx;
  int nfull = nby >> 3;
  int by, bx;
  if (wg < nfull * per) {
    int stripe = wg / per, ins = wg % per;
    by = stripe * 8 + (ins & 7);
    bx = ins >> 3;
  } else {
    int rem = wg - nfull * per;
    int sh = nby - nfull * 8;
    by = nfull * 8 + rem % sh;
    bx = rem / sh;
  }

  int r0 = by * 128;
  int e = 0;
#pragma unroll
  for (int q = 1; q <= 8; q++)
    if (r0 >= base[q]) e = q;

  const u16* Asrc =
      (e == 8) ? (xb + ((size_t)(r0 - base[8]) << 10)) : (Ag + ((size_t)r0 << 10));
  const float* gw = (e == 8) ? sg : (Wg + (size_t)e * 4194304);
  const float* uw = (e == 8) ? su : (Wu + (size_t)e * 4194304);

  int n0 = bx * 128;
  int t = threadIdx.x;
  int trow = t >> 2, tcol = (t & 3) * 8;

  const u16* aP = Asrc + (size_t)trow * 1024 + tcol;
  const float* gP = gw + (size_t)(n0 + trow) * 1024 + tcol;
  const float* uP = uw + (size_t)(n0 + trow) * 1024 + tcol;
  u16* aD = sA + t * 8;
  u16* gD = sBg + t * 8;
  u16* uD = sBu + t * 8;

  int lane = t & 63, wid = t >> 6;
  int wm = wid >> 1, wn = wid & 1;
  int l15 = lane & 15, quad = lane >> 4;
  const u16* aR = sA + (wm * 64 + l15) * 32 + quad * 8;
  const u16* gR = sBg + (wn * 64 + l15) * 32 + quad * 8;
  const u16* uR = sBu + (wn * 64 + l15) * 32 + quad * 8;

  f32x4 accg[4][4] = {};
  f32x4 accu[4][4] = {};

#pragma unroll 1
  for (int kk = 0; kk < 32; kk++) {
    if (kk) __syncthreads();
    GLD16(aP, aD);
    GLD16(aP + 65536, aD + 2048);
    float4 g0 = *(const float4*)gP;
    float4 g1 = *(const float4*)(gP + 4);
    float4 g2 = *(const float4*)(gP + 65536);
    float4 g3 = *(const float4*)(gP + 65540);
    float4 u0 = *(const float4*)uP;
    float4 u1 = *(const float4*)(uP + 4);
    float4 u2 = *(const float4*)(uP + 65536);
    float4 u3 = *(const float4*)(uP + 65540);
    uint4 w0, w1;
    w0.x = cvt2(g0.x, g0.y); w0.y = cvt2(g0.z, g0.w);
    w0.z = cvt2(g1.x, g1.y); w0.w = cvt2(g1.z, g1.w);
    w1.x = cvt2(g2.x, g2.y); w1.y = cvt2(g2.z, g2.w);
    w1.z = cvt2(g3.x, g3.y); w1.w = cvt2(g3.z, g3.w);
    *(uint4*)gD = w0;
    *(uint4*)(gD + 2048) = w1;
    w0.x = cvt2(u0.x, u0.y); w0.y = cvt2(u0.z, u0.w);
    w0.z = cvt2(u1.x, u1.y); w0.w = cvt2(u1.z, u1.w);
    w1.x = cvt2(u2.x, u2.y); w1.y = cvt2(u2.z, u2.w);
    w1.z = cvt2(u3.x, u3.y); w1.w = cvt2(u3.z, u3.w);
    *(uint4*)uD = w0;
    *(uint4*)(uD + 2048) = w1;
    aP += 32;
    gP += 32;
    uP += 32;
    __syncthreads();

    bf16x8 af[4];
#pragma unroll
    for (int i = 0; i < 4; i++) af[i] = *(const bf16x8*)(aR + i * 512);
#pragma unroll
    for (int j = 0; j < 4; j++) {
      bf16x8 bg = *(const bf16x8*)(gR + j * 512);
      bf16x8 bu = *(const bf16x8*)(uR + j * 512);
#pragma unroll
      for (int i = 0; i < 4; i++) {
        accg[i][j] =
            __builtin_amdgcn_mfma_f32_16x16x32_bf16(af[i], bg, accg[i][j], 0, 0, 0);
        accu[i][j] =
            __builtin_amdgcn_mfma_f32_16x16x32_bf16(af[i], bu, accu[i][j], 0, 0, 0);
      }
    }
  }

  // epilogue: h = silu(g)*u ; C/D map: row=(lane>>4)*4+reg, col=lane&15
#pragma unroll
  for (int i = 0; i < 4; i++) {
    int row = r0 + wm * 64 + i * 16 + quad * 4;
#pragma unroll
    for (int r = 0; r < 4; r++) {
      u16* hrow = Hout + (size_t)(row + r) * 4096 + n0 + wn * 64 + l15;
#pragma unroll
      for (int j = 0; j < 4; j++) {
        float g = accg[i][j][r];
        float u = accu[i][j][r];
        float s = g / (1.0f + __expf(-g));
        hrow[j * 16] = bf16of(s * u);
      }
    }
  }
}

// ---------------- GEMM2: out[token] += w * (A@Wd^T) ------------------------
// A [rows,4096] bf16 (Hb), Wd fp32 [E][1024][4096], out [4096,1024] fp32
__global__ __launch_bounds__(256, 3) void gemm2_kernel(
    const u16* __restrict__ A, const float* __restrict__ Wd,
    const float* __restrict__ sd, float* __restrict__ out,
    const int* __restrict__ meta, const int* __restrict__ tlist,
    const float* __restrict__ gwv) {
  __shared__ u16 sA[128 * 32];
  __shared__ u16 sB[128 * 32];

  const int* base = meta + 16;
  int gx = gridDim.x;
  int nby = base[9] >> 7;
  int actz = nby * gx;
  int nact = actz * 2;  // gridDim.z == 2
  int lin = blockIdx.x + gx * (blockIdx.y + gridDim.y * blockIdx.z);
  if (lin >= nact) return;
  int wg = xcd_remap_act(lin, nact);
  int bz = wg / actz;
  int w2 = wg - bz * actz;
  int per = 4 * gx;
  int nfull = nby >> 2;
  int by, bx;
  if (w2 < nfull * per) {
    int stripe = w2 / per, ins = w2 % per;
    by = stripe * 4 + (ins & 3);
    bx = ins >> 2;
  } else {
    int rem = w2 - nfull * per;
    int sh = nby - nfull * 4;
    by = nfull * 4 + rem % sh;
    bx = rem / sh;
  }

  int r0 = by * 128;
  int e = 0;
#pragma unroll
  for (int q = 1; q <= 8; q++)
    if (r0 >= base[q]) e = q;
  const float* dwp = (e == 8) ? sd : (Wd + (size_t)e * 4194304);

  int n0 = bx * 128;
  int k0 = bz * 2048;  // fp32/bf16 element offset in K
  int t = threadIdx.x;
  int trow = t >> 2, tcol = (t & 3) * 8;

  const u16* aP = A + (size_t)(r0 + trow) * 4096 + k0 + tcol;
  const float* bP = dwp + (size_t)(n0 + trow) * 4096 + k0 + tcol;
  u16* aD = sA + t * 8;
  u16* bD = sB + t * 8;

  int lane = t & 63, wid = t >> 6;
  int wm = wid >> 1, wn = wid & 1;
  int l15 = lane & 15, quad = lane >> 4;
  const u16* aR = sA + (wm * 64 + l15) * 32 + quad * 8;
  const u16* bR = sB + (wn * 64 + l15) * 32 + quad * 8;

  f32x4 acc[4][4] = {};

#pragma unroll 1
  for (int kk = 0; kk < 64; kk++) {
    if (kk) __syncthreads();
    GLD16(aP, aD);
    GLD16(aP + 262144, aD + 2048);
    float4 c0 = *(const float4*)bP;
    float4 c1 = *(const float4*)(bP + 4);
    float4 c2 = *(const float4*)(bP + 262144);
    float4 c3 = *(const float4*)(bP + 262148);
    uint4 w0, w1;
    w0.x = cvt2(c0.x, c0.y); w0.y = cvt2(c0.z, c0.w);
    w0.z = cvt2(c1.x, c1.y); w0.w = cvt2(c1.z, c1.w);
    w1.x = cvt2(c2.x, c2.y); w1.y = cvt2(c2.z, c2.w);
    w1.z = cvt2(c3.x, c3.y); w1.w = cvt2(c3.z, c3.w);
    *(uint4*)bD = w0;
    *(uint4*)(bD + 2048) = w1;
    aP += 32;
    bP += 32;
    __syncthreads();

    bf16x8 af[4];
#pragma unroll
    for (int i = 0; i < 4; i++) af[i] = *(const bf16x8*)(aR + i * 512);
#pragma unroll
    for (int j = 0; j < 4; j++) {
      bf16x8 bb = *(const bf16x8*)(bR + j * 512);
#pragma unroll
      for (int i = 0; i < 4; i++)
        acc[i][j] =
            __builtin_amdgcn_mfma_f32_16x16x32_bf16(af[i], bb, acc[i][j], 0, 0, 0);
    }
  }

  int cnt_e = meta[e];  // meta[8] = 4096 (shared)
  int base_e = base[e];
#pragma unroll
  for (int i = 0; i < 4; i++) {
#pragma unroll
    for (int r = 0; r < 4; r++) {
      int s = r0 - base_e + wm * 64 + i * 16 + quad * 4 + r;
      if (s < cnt_e) {
        int tok;
        float w;
        if (e == 8) {
          tok = s;
          w = 1.0f;
        } else {
          tok = tlist[e * 4096 + s];
          w = gwv[e * 4096 + s];
        }
        float* orow = out + (size_t)tok * 1024 + n0 + wn * 64 + l15;
#pragma unroll
        for (int j = 0; j < 4; j++) unsafeAtomicAdd(orow + j * 16, w * acc[i][j][r]);
      }
    }
  }
}

// ---------------------------------------------------------------------------
extern "C" void kernel_launch(void* const* d_in, const int* in_sizes, int n_in,
                              void* d_out, int out_size, void* d_ws,
                              size_t ws_size, hipStream_t stream) {
  const float* x = (const float*)d_in[0];
  const float* rw = (const float*)d_in[1];
  const float* gw_ = (const float*)d_in[2];
  const float* uw_ = (const float*)d_in[3];
  const float* dw_ = (const float*)d_in[4];
  const float* sg = (const float*)d_in[5];
  const float* su = (const float*)d_in[6];
  const float* sd = (const float*)d_in[7];
  float* out = (float*)d_out;
  char* ws = (char*)d_ws;

  int* meta = (int*)(ws + 0);
  int* tlist = (int*)(ws + 256);
  float* gwv = (float*)(ws + 131328);
  u16* xb = (u16*)(ws + 262400);      // 4096 x 1024 bf16
  u16* Ag = (u16*)(ws + 8651008);     // <=9216 x 1024 bf16
  u16* Hb = (u16*)(ws + 27525376);    // <=13312 x 4096 bf16 (routed+shared)

  zero_meta_kernel<<<1, 64, 0, stream>>>(meta);
  router_kernel<<<4096, 64, 0, stream>>>(x, rw, xb, tlist, gwv, meta);
  finalize_kernel<<<1, 64, 0, stream>>>(meta, out);
  gather_kernel<<<9216, 128, 0, stream>>>(xb, Ag, tlist, meta);
  zero_out_kernel<<<4096, 256, 0, stream>>>((float4*)out);

  // GEMM1: all 8 routed experts + shared (expert 8), one dispatch.
  // grid.y = max tiles: (9216 + 4096) / 128 = 104
  gemm1_kernel<<<dim3(32, 104), 256, 0, stream>>>(Ag, xb, gw_, uw_, sg, su, Hb,
                                                  meta);
  // GEMM2: one dispatch, K split in 2 (z), all-atomic epilogue.
  gemm2_kernel<<<dim3(8, 104, 2), 256, 0, stream>>>(Hb, dw_, sd, out, meta,
                                                    tlist, gwv);
}